// Round 14
// baseline (220.906 us; speedup 1.0000x reference)
//
#include <hip/hip_runtime.h>
#include <hip/hip_bf16.h>

typedef __attribute__((ext_vector_type(8))) short sh8;
typedef __attribute__((ext_vector_type(4))) float f32x4;

#define MFMA16(a, b, c) __builtin_amdgcn_mfma_f32_16x16x32_bf16((a), (b), (c), 0, 0, 0)

__device__ __forceinline__ unsigned short f2bf(float f) {
    return (unsigned short)((__float_as_uint(f) + 0x8000u) >> 16);
}
__device__ __forceinline__ unsigned int pack2bf(float lo, float hi) {
    unsigned int ul = __float_as_uint(lo) + 0x8000u;
    unsigned int uh = __float_as_uint(hi) + 0x8000u;
    return __builtin_amdgcn_perm(uh, ul, 0x07060302u);
}
__device__ __forceinline__ float redmax_hi(float x) {
    x = fmaxf(x, __shfl_xor(x, 16, 64));
    return fmaxf(x, __shfl_xor(x, 32, 64));
}
__device__ __forceinline__ float redsum_hi(float x) {
    x += __shfl_xor(x, 16, 64);
    return x + __shfl_xor(x, 32, 64);
}
// async global->LDS, 16B per lane; LDS dest = wave-uniform base + lane*16
__device__ __forceinline__ void gload_lds16(const void* g, void* l) {
    __builtin_amdgcn_global_load_lds(
        (const __attribute__((address_space(1))) unsigned int*)g,
        (__attribute__((address_space(3))) unsigned int*)l, 16, 0, 0);
}

// ---------------------------------------------------------------------------
// f32 -> bf16 converters (run once)
// ---------------------------------------------------------------------------
__global__ __launch_bounds__(256) void cvt_x_k(
    const float* __restrict__ src, unsigned short* __restrict__ dst, int n4)
{
    int i = blockIdx.x * 256 + threadIdx.x;
    int stride = gridDim.x * 256;
    for (; i < n4; i += stride) {
        float4 v = ((const float4*)src)[i];
        uint2 h = { pack2bf(v.x, v.y), pack2bf(v.z, v.w) };
        ((uint2*)dst)[i] = h;
    }
}
__global__ __launch_bounds__(256) void cvt_w_k(
    const float* __restrict__ Wq, const float* __restrict__ Wk,
    const float* __restrict__ Wv, const float* __restrict__ Wo,
    unsigned short* __restrict__ wbf)
{
    int i = blockIdx.x * 256 + threadIdx.x;   // over 4*262144 float4s
    int seg = i >> 18;
    int off = i & 0x3FFFF;
    const float* s = (seg < 2) ? ((seg == 0) ? Wq : Wk) : ((seg == 2) ? Wv : Wo);
    float4 v = ((const float4*)s)[off];
    uint2 h = { pack2bf(v.x, v.y), pack2bf(v.z, v.w) };
    ((uint2*)wbf)[i] = h;
}

// ---------------------------------------------------------------------------
// Mask compaction (unchanged): list of kv indices with mask!=0.
// ---------------------------------------------------------------------------
__global__ __launch_bounds__(64) void compact_k(
    const int* __restrict__ mask, int* __restrict__ idx, int* __restrict__ cnt)
{
    const int b = blockIdx.x, l = threadIdx.x;
    const int* mb = mask + b * 2048;
    int base = 0;
    for (int i = 0; i < 32; ++i) {
        int m = mb[i * 64 + l];
        unsigned long long bal = __ballot(m != 0);
        int pre = __popcll(bal & ((1ull << l) - 1ull));
        if (m) idx[b * 2048 + base + pre] = i * 64 + l;
        base += (int)__popcll(bal);
    }
    if (base == 0) {
        for (int i = l; i < 2048; i += 64) idx[b * 2048 + i] = i;
        base = 2048;
    }
    if (l == 0) cnt[b] = base;
}

// ---------------------------------------------------------------------------
// Gather compacted K rows -> Kck[b][row][1024] (4 MB/batch).
// ---------------------------------------------------------------------------
__global__ __launch_bounds__(256) void kvgather_k(
    const unsigned short* __restrict__ qkv, const int* __restrict__ idx,
    const int* __restrict__ cnt, unsigned short* __restrict__ Kck, int b0)
{
    const int b = blockIdx.z;
    const int t = blockIdx.y;
    const int z = blockIdx.x;          // row octet 0..7
    const int nc = cnt[b0 + b];
    if (t * 64 >= ((nc + 63) & ~63)) return;
    const int* idxb = idx + (size_t)(b0 + b) * 2048;
    const int tid = threadIdx.x;
    unsigned short* dst_b = Kck + (size_t)b * 2048 * 1024;
#pragma unroll
    for (int p = 0; p < 4; ++p) {
        int i = p * 256 + tid;                 // 0..1023
        int r = t * 64 + z * 8 + (i >> 7);
        int c = i & 127;
        int src = idxb[min(r, nc - 1)];
        uint4 v = *(const uint4*)&qkv[((size_t)b * 2048 + src) * 3072 + 1024 + c * 8];
        *(uint4*)&dst_b[(size_t)r * 1024 + c * 8] = v;
    }
}

// ---------------------------------------------------------------------------
// Gather+transpose V directly from qkv -> Vtg[b][h][d=64][kv=2048].
// ---------------------------------------------------------------------------
__global__ __launch_bounds__(256) void vtrans_k(
    const unsigned short* __restrict__ qkv, const int* __restrict__ idx,
    const int* __restrict__ cnt, unsigned short* __restrict__ Vtg, int b0)
{
    __shared__ unsigned short Ls[128][72];
    const int kb = blockIdx.x;      // kv block of 128
    const int h  = blockIdx.y;
    const int b  = blockIdx.z;
    const int nc = cnt[b0 + b];
    if (kb * 128 >= ((nc + 63) & ~63)) return;
    const int* idxb = idx + (size_t)(b0 + b) * 2048;
    const int tid = threadIdx.x;
#pragma unroll
    for (int p = 0; p < 4; ++p) {
        int i = p * 256 + tid;
        int r = i >> 3, c = i & 7;
        int src = idxb[min(kb * 128 + r, nc - 1)];
        uint4 v = *(const uint4*)&qkv[((size_t)b * 2048 + src) * 3072 + 2048 + h * 64 + c * 8];
        *(uint4*)&Ls[r][c * 8] = v;
    }
    __syncthreads();
    unsigned short* dst = Vtg + ((size_t)b * 16 + h) * 64 * 2048;
#pragma unroll
    for (int p = 0; p < 4; ++p) {
        int i = p * 256 + tid;
        int d = i >> 4, kc = i & 15;
        unsigned int wv[4];
#pragma unroll
        for (int j = 0; j < 4; ++j) {
            unsigned int lo = Ls[kc * 8 + 2 * j][d];
            unsigned int hv = Ls[kc * 8 + 2 * j + 1][d];
            wv[j] = lo | (hv << 16);
        }
        *(uint4*)&dst[(size_t)d * 2048 + kb * 128 + kc * 8] = *(uint4*)wv;
    }
}

// ---------------------------------------------------------------------------
// QKV projection, m97-style (unchanged).
// ---------------------------------------------------------------------------
__global__ __launch_bounds__(256) void gemm_qkv_k(
    const unsigned short* __restrict__ xbf,
    const unsigned short* __restrict__ wbf,
    unsigned short* __restrict__ qkv)
{
    __shared__ unsigned short As[128][32];
    __shared__ unsigned short Bs[128][32];
    const int tid = threadIdx.x;
    const int l = tid & 63, w = tid >> 6;
    const int wr = w >> 1, wc = w & 1;
    const long row0 = (long)blockIdx.y * 128;
    const int col0 = blockIdx.x * 128;

    f32x4 acc[4][4] = {};
    const int fr = l & 15, hi = l >> 4;

    const int sr = tid >> 2;
    const int sc = (tid & 3) * 8;
    const unsigned short* ga = &xbf[(row0 + sr) * 1024 + sc];
    const unsigned short* gb = &wbf[(long)(col0 + sr) * 1024 + sc];
    unsigned short* la = &As[w * 16][0];
    unsigned short* lb = &Bs[w * 16][0];

    for (int k0 = 0; k0 < 1024; k0 += 32) {
        __syncthreads();
        gload_lds16(ga + k0, la);
        gload_lds16(ga + 64 * 1024 + k0, la + 64 * 32);
        gload_lds16(gb + k0, lb);
        gload_lds16(gb + 64 * 1024 + k0, lb + 64 * 32);
        __syncthreads();

        sh8 af[4], bf[4];
#pragma unroll
        for (int i = 0; i < 4; ++i) {
            af[i] = *(const sh8*)&As[wr * 64 + i * 16 + fr][hi * 8];
            bf[i] = *(const sh8*)&Bs[wc * 64 + i * 16 + fr][hi * 8];
        }
#pragma unroll
        for (int i = 0; i < 4; ++i)
#pragma unroll
            for (int j = 0; j < 4; ++j)
                acc[i][j] = MFMA16(af[i], bf[j], acc[i][j]);
    }

    const float scale = (col0 < 1024) ? 0.1803368801f : 1.0f;
    const int rg = hi * 4, cg = l & 15;
#pragma unroll
    for (int i = 0; i < 4; ++i)
#pragma unroll
        for (int j = 0; j < 4; ++j) {
            long gr = row0 + wr * 64 + i * 16 + rg;
            int gc = col0 + wc * 64 + j * 16 + cg;
#pragma unroll
            for (int r = 0; r < 4; ++r)
                qkv[(gr + r) * 3072 + gc] = f2bf(acc[i][j][r] * scale);
        }
}

// ---------------------------------------------------------------------------
// Flash attention. R14 = R12 (1 q-group/wave, 64 q/block, K/V gload_lds)
// + DOUBLE-BUFFERED single-barrier staging: prologue stages tile 0; each
// iteration's __syncthreads() (vmcnt 0) drains tile t, then tile t+1's
// loads are issued into buf^1 and overlap tile t's compute (T3 2-phase).
// R12 had zero load/compute overlap (loads issued+drained between two
// barriers); R13's 2-group variant hit the VGPR occupancy cliff (reverted).
// ---------------------------------------------------------------------------
__global__ __launch_bounds__(256) void attn_k(
    const unsigned short* __restrict__ qkv, const unsigned short* __restrict__ Kck,
    const unsigned short* __restrict__ Vtg, const int* __restrict__ cnt,
    unsigned short* __restrict__ ao, int b0)
{
    __shared__ unsigned short Kl[2][64][64];
    __shared__ unsigned short Vt[2][64][64];
    __shared__ float biasf[64];
    __shared__ unsigned short Pl[4][16][72];

    const int tid = threadIdx.x;
    const int l = tid & 63, w = tid >> 6;
    const int fr = l & 15, hi = l >> 4;

    // T1: bijective XCD swizzle
    int nwg = gridDim.x;
    int wgid = ((nwg & 7) == 0) ? ((blockIdx.x & 7) * (nwg >> 3) + (blockIdx.x >> 3))
                                : blockIdx.x;
    const int qb = wgid & 31;
    const int h  = (wgid >> 5) & 15;
    const int b  = wgid >> 9;
    const int q0 = qb * 64;
    const long base = (long)b * 2048;

    const int nc = cnt[b0 + b];
    const int nt = (nc + 63) >> 6;

    sh8 qf0, qf1;
    {
        const unsigned short* qp = &qkv[(base + q0 + w * 16 + fr) * 3072 + h * 64 + hi * 8];
        qf0 = *(const sh8*)qp;
        qf1 = *(const sh8*)(qp + 32);
    }

    f32x4 acc[4] = {};
    float mrow = -1e30f;
    float lrow = 0.f;

    const long TSK = 131072;                      // 64 rows * 2048 B per K tile
    const char* kck_b = (const char*)Kck + (size_t)b * 2048 * 2048;

    const int l8 = l >> 3, c8 = l & 7;
    const char* ksrc = kck_b + (size_t)(w * 16 + l8) * 2048 + h * 128 + ((c8 ^ l8) * 16);

    const char* vtg_h = (const char*)Vtg + ((size_t)b * 16 + h) * 64 * 4096;
    const int d0 = w * 16 + l8, d1 = d0 + 8;
    const int fd0 = (d0 & 7) ^ (d0 >> 3), fd1 = (d1 & 7) ^ (d1 >> 3);
    const char* vsrc0 = vtg_h + (size_t)d0 * 4096 + ((c8 ^ fd0) * 16);
    const char* vsrc1 = vtg_h + (size_t)d1 * 4096 + ((c8 ^ fd1) * 16);

    // bias for the LAST tile only (full tiles all-valid by compaction)
    if (tid < 64) biasf[tid] = ((nt - 1) * 64 + tid < nc) ? 0.0f : -1e9f;

    // prologue: stage tile 0 into buffer 0
    gload_lds16(ksrc, &Kl[0][w * 16][0]);
    gload_lds16(ksrc + 8 * 2048, &Kl[0][w * 16 + 8][0]);
    ksrc += TSK;
    gload_lds16(vsrc0, &Vt[0][w * 16][0]);
    gload_lds16(vsrc1, &Vt[0][w * 16 + 8][0]);
    vsrc0 += 128; vsrc1 += 128;

    for (int t = 0; t < nt; ++t) {
        __syncthreads();   // vmcnt(0): tile t resident; all waves done with buf^1
        const int cur = t & 1;
        if (t + 1 < nt) {  // issue tile t+1 into the other buffer (overlaps compute)
            const int nxt = cur ^ 1;
            gload_lds16(ksrc, &Kl[nxt][w * 16][0]);
            gload_lds16(ksrc + 8 * 2048, &Kl[nxt][w * 16 + 8][0]);
            ksrc += TSK;
            gload_lds16(vsrc0, &Vt[nxt][w * 16][0]);
            gload_lds16(vsrc1, &Vt[nxt][w * 16 + 8][0]);
            vsrc0 += 128; vsrc1 += 128;
        }

        // K fragments
        sh8 kf[4][2];
#pragma unroll
        for (int tt = 0; tt < 4; ++tt) {
            const unsigned short* kp = &Kl[cur][tt * 16 + fr][0];
#pragma unroll
            for (int c = 0; c < 2; ++c)
                kf[tt][c] = *(const sh8*)&kp[((4 * c + hi) ^ (fr & 7)) * 8];
        }

        // S^T = K Q
        f32x4 s[4] = {};
        __builtin_amdgcn_s_setprio(1);
#pragma unroll
        for (int tt = 0; tt < 4; ++tt) {
            s[tt] = MFMA16(kf[tt][0], qf0, s[tt]);
            s[tt] = MFMA16(kf[tt][1], qf1, s[tt]);
        }
        __builtin_amdgcn_s_setprio(0);

        if (t == nt - 1) {                // mask bias: last tile only
#pragma unroll
            for (int tt = 0; tt < 4; ++tt)
                s[tt] += *(const f32x4*)&biasf[tt * 16 + 4 * hi];
        }

        float pm = s[0][0];
#pragma unroll
        for (int tt = 0; tt < 4; ++tt)
#pragma unroll
            for (int r = 0; r < 4; ++r) pm = fmaxf(pm, s[tt][r]);
        pm = redmax_hi(pm);

        if (!__all(pm <= mrow)) {           // defer-max: wave-uniform skip
            float mn = fmaxf(mrow, pm);
            float scl = __builtin_amdgcn_exp2f(mrow - mn);
            lrow *= scl;
#pragma unroll
            for (int df = 0; df < 4; ++df) acc[df] *= scl;
            mrow = mn;
        }

        float ps = 0.f;
#pragma unroll
        for (int tt = 0; tt < 4; ++tt)
#pragma unroll
            for (int r = 0; r < 4; ++r) {
                float p = __builtin_amdgcn_exp2f(s[tt][r] - mrow);
                s[tt][r] = p;
                ps += p;
            }
        lrow += redsum_hi(ps);

        // P -> per-wave LDS (4x b64)
#pragma unroll
        for (int tt = 0; tt < 4; ++tt) {
            uint2 pw = { pack2bf(s[tt][0], s[tt][1]), pack2bf(s[tt][2], s[tt][3]) };
            *(uint2*)&Pl[w][fr][tt * 16 + hi * 4] = pw;
        }

        // O^T += V^T * P
#pragma unroll
        for (int c = 0; c < 2; ++c) {
            sh8 pa = *(const sh8*)&Pl[w][fr][c * 32 + hi * 8];
            __builtin_amdgcn_s_setprio(1);
#pragma unroll
            for (int df = 0; df < 4; ++df) {
                int d = df * 16 + fr;
                int fd = (d & 7) ^ (d >> 3);
                sh8 vfr = *(const sh8*)&Vt[cur][d][((4 * c + hi) ^ fd) * 8];
                acc[df] = MFMA16(vfr, pa, acc[df]);
            }
            __builtin_amdgcn_s_setprio(0);
        }
    }

    {
        float inv = 1.0f / lrow;
        long qr = base + q0 + w * 16 + fr;
        unsigned short* op = &ao[qr * 1024 + h * 64];
#pragma unroll
        for (int df = 0; df < 4; ++df) {
            f32x4 o = acc[df];
            uint2 ow = { pack2bf(o[0] * inv, o[1] * inv), pack2bf(o[2] * inv, o[3] * inv) };
            *(uint2*)&op[df * 16 + hi * 4] = ow;
        }
    }
}

// ---------------------------------------------------------------------------
// Output projection, m97-style staging (unchanged).
// ---------------------------------------------------------------------------
__global__ __launch_bounds__(256) void gemm_out_k(
    const unsigned short* __restrict__ ao, const unsigned short* __restrict__ wob,
    const float* __restrict__ bo, float* __restrict__ out)
{
    __shared__ unsigned short As[128][32];
    __shared__ unsigned short Bs[128][32];
    const int tid = threadIdx.x;
    const int l = tid & 63, w = tid >> 6;
    const int wr = w >> 1, wc = w & 1;
    const long row0 = (long)blockIdx.y * 128;
    const int col0 = blockIdx.x * 128;

    f32x4 acc[4][4] = {};
    const int fr = l & 15, hi = l >> 4;

    const int sr = tid >> 2;
    const int sc = (tid & 3) * 8;
    const unsigned short* ga = &ao[(row0 + sr) * 1024 + sc];
    const unsigned short* gb = &wob[(long)(col0 + sr) * 1024 + sc];
    unsigned short* la = &As[w * 16][0];
    unsigned short* lb = &Bs[w * 16][0];

    for (int k0 = 0; k0 < 1024; k0 += 32) {
        __syncthreads();
        gload_lds16(ga + k0, la);
        gload_lds16(ga + 64 * 1024 + k0, la + 64 * 32);
        gload_lds16(gb + k0, lb);
        gload_lds16(gb + 64 * 1024 + k0, lb + 64 * 32);
        __syncthreads();

        sh8 af[4], bf[4];
#pragma unroll
        for (int i = 0; i < 4; ++i) {
            af[i] = *(const sh8*)&As[wr * 64 + i * 16 + fr][hi * 8];
            bf[i] = *(const sh8*)&Bs[wc * 64 + i * 16 + fr][hi * 8];
        }
#pragma unroll
        for (int i = 0; i < 4; ++i)
#pragma unroll
            for (int j = 0; j < 4; ++j)
                acc[i][j] = MFMA16(af[i], bf[j], acc[i][j]);
    }

    const int rg = hi * 4, cg = l & 15;
#pragma unroll
    for (int i = 0; i < 4; ++i)
#pragma unroll
        for (int j = 0; j < 4; ++j) {
            long gr = row0 + wr * 64 + i * 16 + rg;
            int gc = col0 + wc * 64 + j * 16 + cg;
            float bb = bo[gc];
#pragma unroll
            for (int r = 0; r < 4; ++r)
                out[(gr + r) * 1024 + gc] = acc[i][j][r] + bb;
        }
}

extern "C" void kernel_launch(void* const* d_in, const int* in_sizes, int n_in,
                              void* d_out, int out_size, void* d_ws, size_t ws_size,
                              hipStream_t stream) {
    const float* x    = (const float*)d_in[0];
    const int*   mask = (const int*)d_in[1];
    const float* Wq   = (const float*)d_in[2];
    const float* Wk   = (const float*)d_in[3];
    const float* Wv   = (const float*)d_in[4];
    const float* Wo   = (const float*)d_in[5];
    const float* bo   = (const float*)d_in[6];
    float* out = (float*)d_out;

    const size_t wbf_bytes = (size_t)4096 * 1024 * 2;              // 8 MiB
    const size_t idx_bytes = (size_t)4 * 2048 * 4 + 64;
    const size_t xbf_per_b = (size_t)2048 * 1024 * 2;              // 4 MiB
    const size_t qkv_per_b = (size_t)2048 * 3072 * 2;              // 12 MiB
    const size_t ao_per_b  = (size_t)2048 * 1024 * 2;              // 4 MiB
    const size_t kck_per_b = (size_t)2048 * 1024 * 2;              // 4 MiB
    const size_t vt_per_b  = (size_t)16 * 64 * 2048 * 2;           // 4 MiB
    const size_t per_b = xbf_per_b + qkv_per_b + ao_per_b + kck_per_b + vt_per_b; // 28 MiB

    size_t fixed = wbf_bytes + idx_bytes;
    size_t avail = (ws_size > fixed) ? (ws_size - fixed) : 0;
    int bchunk = (avail >= per_b) ? (int)(avail / per_b) : 1;
    if (bchunk > 4) bchunk = 4;

    char* p = (char*)d_ws;
    unsigned short* wbf = (unsigned short*)p;            p += wbf_bytes;
    int* idxp = (int*)p;                                 p += (size_t)4 * 2048 * 4;
    int* cntp = (int*)p;                                 p += 64;
    unsigned short* xbf = (unsigned short*)p;            p += (size_t)bchunk * xbf_per_b;
    unsigned short* qkv = (unsigned short*)p;            p += (size_t)bchunk * qkv_per_b;
    unsigned short* ao  = (unsigned short*)p;            p += (size_t)bchunk * ao_per_b;
    unsigned short* Kck = (unsigned short*)p;            p += (size_t)bchunk * kck_per_b;
    unsigned short* Vtg = (unsigned short*)p;

    cvt_w_k<<<4096, 256, 0, stream>>>(Wq, Wk, Wv, Wo, wbf);
    compact_k<<<4, 64, 0, stream>>>(mask, idxp, cntp);

    for (int b0 = 0; b0 < 4; b0 += bchunk) {
        int bc = (4 - b0 < bchunk) ? (4 - b0) : bchunk;
        cvt_x_k<<<2048, 256, 0, stream>>>(
            x + (size_t)b0 * 2048 * 1024, xbf, bc * 524288);
        gemm_qkv_k<<<dim3(24, bc * 16), 256, 0, stream>>>(xbf, wbf, qkv);
        kvgather_k<<<dim3(8, 32, bc), 256, 0, stream>>>(qkv, idxp, cntp, Kck, b0);
        vtrans_k<<<dim3(16, 16, bc), 256, 0, stream>>>(qkv, idxp, cntp, Vtg, b0);
        attn_k<<<dim3(512 * bc), 256, 0, stream>>>(qkv, Kck, Vtg, cntp, ao, b0);
        gemm_out_k<<<dim3(8, bc * 16), 256, 0, stream>>>(
            ao, wbf + (size_t)3072 * 1024, bo, out + (size_t)b0 * 2048 * 1024);
    }
}

// Round 15
// 216.254 us; speedup vs baseline: 1.0215x; 1.0215x over previous
//
#include <hip/hip_runtime.h>
#include <hip/hip_bf16.h>

typedef __attribute__((ext_vector_type(8))) short sh8;
typedef __attribute__((ext_vector_type(4))) float f32x4;

#define MFMA16(a, b, c) __builtin_amdgcn_mfma_f32_16x16x32_bf16((a), (b), (c), 0, 0, 0)

__device__ __forceinline__ unsigned short f2bf(float f) {
    return (unsigned short)((__float_as_uint(f) + 0x8000u) >> 16);
}
__device__ __forceinline__ unsigned int pack2bf(float lo, float hi) {
    unsigned int ul = __float_as_uint(lo) + 0x8000u;
    unsigned int uh = __float_as_uint(hi) + 0x8000u;
    return __builtin_amdgcn_perm(uh, ul, 0x07060302u);
}
__device__ __forceinline__ float redmax_hi(float x) {
    x = fmaxf(x, __shfl_xor(x, 16, 64));
    return fmaxf(x, __shfl_xor(x, 32, 64));
}
__device__ __forceinline__ float redsum_hi(float x) {
    x += __shfl_xor(x, 16, 64);
    return x + __shfl_xor(x, 32, 64);
}
// async global->LDS, 16B per lane; LDS dest = wave-uniform base + lane*16
__device__ __forceinline__ void gload_lds16(const void* g, void* l) {
    __builtin_amdgcn_global_load_lds(
        (const __attribute__((address_space(1))) unsigned int*)g,
        (__attribute__((address_space(3))) unsigned int*)l, 16, 0, 0);
}

// ---------------------------------------------------------------------------
// f32 -> bf16 converters (run once)
// ---------------------------------------------------------------------------
__global__ __launch_bounds__(256) void cvt_x_k(
    const float* __restrict__ src, unsigned short* __restrict__ dst, int n4)
{
    int i = blockIdx.x * 256 + threadIdx.x;
    int stride = gridDim.x * 256;
    for (; i < n4; i += stride) {
        float4 v = ((const float4*)src)[i];
        uint2 h = { pack2bf(v.x, v.y), pack2bf(v.z, v.w) };
        ((uint2*)dst)[i] = h;
    }
}
__global__ __launch_bounds__(256) void cvt_w_k(
    const float* __restrict__ Wq, const float* __restrict__ Wk,
    const float* __restrict__ Wv, const float* __restrict__ Wo,
    unsigned short* __restrict__ wbf)
{
    int i = blockIdx.x * 256 + threadIdx.x;   // over 4*262144 float4s
    int seg = i >> 18;
    int off = i & 0x3FFFF;
    const float* s = (seg < 2) ? ((seg == 0) ? Wq : Wk) : ((seg == 2) ? Wv : Wo);
    float4 v = ((const float4*)s)[off];
    uint2 h = { pack2bf(v.x, v.y), pack2bf(v.z, v.w) };
    ((uint2*)wbf)[i] = h;
}

// ---------------------------------------------------------------------------
// Mask compaction (unchanged): list of kv indices with mask!=0.
// ---------------------------------------------------------------------------
__global__ __launch_bounds__(64) void compact_k(
    const int* __restrict__ mask, int* __restrict__ idx, int* __restrict__ cnt)
{
    const int b = blockIdx.x, l = threadIdx.x;
    const int* mb = mask + b * 2048;
    int base = 0;
    for (int i = 0; i < 32; ++i) {
        int m = mb[i * 64 + l];
        unsigned long long bal = __ballot(m != 0);
        int pre = __popcll(bal & ((1ull << l) - 1ull));
        if (m) idx[b * 2048 + base + pre] = i * 64 + l;
        base += (int)__popcll(bal);
    }
    if (base == 0) {
        for (int i = l; i < 2048; i += 64) idx[b * 2048 + i] = i;
        base = 2048;
    }
    if (l == 0) cnt[b] = base;
}

// ---------------------------------------------------------------------------
// Gather compacted K rows -> Kck[b][row][1024] (4 MB/batch).
// ---------------------------------------------------------------------------
__global__ __launch_bounds__(256) void kvgather_k(
    const unsigned short* __restrict__ qkv, const int* __restrict__ idx,
    const int* __restrict__ cnt, unsigned short* __restrict__ Kck, int b0)
{
    const int b = blockIdx.z;
    const int t = blockIdx.y;
    const int z = blockIdx.x;          // row octet 0..7
    const int nc = cnt[b0 + b];
    if (t * 64 >= ((nc + 63) & ~63)) return;
    const int* idxb = idx + (size_t)(b0 + b) * 2048;
    const int tid = threadIdx.x;
    unsigned short* dst_b = Kck + (size_t)b * 2048 * 1024;
#pragma unroll
    for (int p = 0; p < 4; ++p) {
        int i = p * 256 + tid;                 // 0..1023
        int r = t * 64 + z * 8 + (i >> 7);
        int c = i & 127;
        int src = idxb[min(r, nc - 1)];
        uint4 v = *(const uint4*)&qkv[((size_t)b * 2048 + src) * 3072 + 1024 + c * 8];
        *(uint4*)&dst_b[(size_t)r * 1024 + c * 8] = v;
    }
}

// ---------------------------------------------------------------------------
// Gather+transpose V directly from qkv -> Vtg[b][h][d=64][kv=2048].
// ---------------------------------------------------------------------------
__global__ __launch_bounds__(256) void vtrans_k(
    const unsigned short* __restrict__ qkv, const int* __restrict__ idx,
    const int* __restrict__ cnt, unsigned short* __restrict__ Vtg, int b0)
{
    __shared__ unsigned short Ls[128][72];
    const int kb = blockIdx.x;      // kv block of 128
    const int h  = blockIdx.y;
    const int b  = blockIdx.z;
    const int nc = cnt[b0 + b];
    if (kb * 128 >= ((nc + 63) & ~63)) return;
    const int* idxb = idx + (size_t)(b0 + b) * 2048;
    const int tid = threadIdx.x;
#pragma unroll
    for (int p = 0; p < 4; ++p) {
        int i = p * 256 + tid;
        int r = i >> 3, c = i & 7;
        int src = idxb[min(kb * 128 + r, nc - 1)];
        uint4 v = *(const uint4*)&qkv[((size_t)b * 2048 + src) * 3072 + 2048 + h * 64 + c * 8];
        *(uint4*)&Ls[r][c * 8] = v;
    }
    __syncthreads();
    unsigned short* dst = Vtg + ((size_t)b * 16 + h) * 64 * 2048;
#pragma unroll
    for (int p = 0; p < 4; ++p) {
        int i = p * 256 + tid;
        int d = i >> 4, kc = i & 15;
        unsigned int wv[4];
#pragma unroll
        for (int j = 0; j < 4; ++j) {
            unsigned int lo = Ls[kc * 8 + 2 * j][d];
            unsigned int hv = Ls[kc * 8 + 2 * j + 1][d];
            wv[j] = lo | (hv << 16);
        }
        *(uint4*)&dst[(size_t)d * 2048 + kb * 128 + kc * 8] = *(uint4*)wv;
    }
}

// ---------------------------------------------------------------------------
// QKV projection, m97-style (unchanged).
// ---------------------------------------------------------------------------
__global__ __launch_bounds__(256) void gemm_qkv_k(
    const unsigned short* __restrict__ xbf,
    const unsigned short* __restrict__ wbf,
    unsigned short* __restrict__ qkv)
{
    __shared__ unsigned short As[128][32];
    __shared__ unsigned short Bs[128][32];
    const int tid = threadIdx.x;
    const int l = tid & 63, w = tid >> 6;
    const int wr = w >> 1, wc = w & 1;
    const long row0 = (long)blockIdx.y * 128;
    const int col0 = blockIdx.x * 128;

    f32x4 acc[4][4] = {};
    const int fr = l & 15, hi = l >> 4;

    const int sr = tid >> 2;
    const int sc = (tid & 3) * 8;
    const unsigned short* ga = &xbf[(row0 + sr) * 1024 + sc];
    const unsigned short* gb = &wbf[(long)(col0 + sr) * 1024 + sc];
    unsigned short* la = &As[w * 16][0];
    unsigned short* lb = &Bs[w * 16][0];

    for (int k0 = 0; k0 < 1024; k0 += 32) {
        __syncthreads();
        gload_lds16(ga + k0, la);
        gload_lds16(ga + 64 * 1024 + k0, la + 64 * 32);
        gload_lds16(gb + k0, lb);
        gload_lds16(gb + 64 * 1024 + k0, lb + 64 * 32);
        __syncthreads();

        sh8 af[4], bf[4];
#pragma unroll
        for (int i = 0; i < 4; ++i) {
            af[i] = *(const sh8*)&As[wr * 64 + i * 16 + fr][hi * 8];
            bf[i] = *(const sh8*)&Bs[wc * 64 + i * 16 + fr][hi * 8];
        }
#pragma unroll
        for (int i = 0; i < 4; ++i)
#pragma unroll
            for (int j = 0; j < 4; ++j)
                acc[i][j] = MFMA16(af[i], bf[j], acc[i][j]);
    }

    const float scale = (col0 < 1024) ? 0.1803368801f : 1.0f;
    const int rg = hi * 4, cg = l & 15;
#pragma unroll
    for (int i = 0; i < 4; ++i)
#pragma unroll
        for (int j = 0; j < 4; ++j) {
            long gr = row0 + wr * 64 + i * 16 + rg;
            int gc = col0 + wc * 64 + j * 16 + cg;
#pragma unroll
            for (int r = 0; r < 4; ++r)
                qkv[(gr + r) * 3072 + gc] = f2bf(acc[i][j][r] * scale);
        }
}

// ---------------------------------------------------------------------------
// Flash attention. R15 = R12 (single-buffer 26KB LDS, 1 q-group/wave) with
// T14 issue-early/consume-late staging: loads for tile t+1 are issued AFTER
// the lgkm barrier and consumed at the NEXT iteration's barrier, so they
// overlap the whole softmax+PV phase. Reg-staging is now ~free (linear
// sources, 4 loads + 4 ds_write_b128 to compile-time-constant swizzled
// dests). LDS/VGPR tier unchanged vs R12 (R13 VGPR-cliff and R14 LDS-cliff
// both regressed — occupancy is the governing resource).
// Content convention identical to R12: row r holds global chunk c at LDS
// chunk c^(r&7) (K), c^fd (V) — read side byte-identical.
// ---------------------------------------------------------------------------
__global__ __launch_bounds__(256) void attn_k(
    const unsigned short* __restrict__ qkv, const unsigned short* __restrict__ Kck,
    const unsigned short* __restrict__ Vtg, const int* __restrict__ cnt,
    unsigned short* __restrict__ ao, int b0)
{
    __shared__ unsigned short Kl[64][64];
    __shared__ unsigned short Vt[64][64];
    __shared__ float biasf[64];
    __shared__ unsigned short Pl[4][16][72];

    const int tid = threadIdx.x;
    const int l = tid & 63, w = tid >> 6;
    const int fr = l & 15, hi = l >> 4;

    // T1: bijective XCD swizzle
    int nwg = gridDim.x;
    int wgid = ((nwg & 7) == 0) ? ((blockIdx.x & 7) * (nwg >> 3) + (blockIdx.x >> 3))
                                : blockIdx.x;
    const int qb = wgid & 31;
    const int h  = (wgid >> 5) & 15;
    const int b  = wgid >> 9;
    const int q0 = qb * 64;
    const long base = (long)b * 2048;

    const int nc = cnt[b0 + b];
    const int nt = (nc + 63) >> 6;

    sh8 qf0, qf1;
    {
        const unsigned short* qp = &qkv[(base + q0 + w * 16 + fr) * 3072 + h * 64 + hi * 8];
        qf0 = *(const sh8*)qp;
        qf1 = *(const sh8*)(qp + 32);
    }

    f32x4 acc[4] = {};
    float mrow = -1e30f;
    float lrow = 0.f;

    const long TSK = 131072;                      // 64 rows * 2048 B per K tile
    const char* kck_b = (const char*)Kck + (size_t)b * 2048 * 2048;
    const char* vtg_h = (const char*)Vtg + ((size_t)b * 16 + h) * 64 * 4096;

    const int l8 = l >> 3, c8 = l & 7;
    // linear global sources (fully coalesced), bumped per tile
    const char* ksrc = kck_b + (size_t)(w * 16 + l8) * 2048 + h * 128 + c8 * 16;
    const int d0 = w * 16 + l8, d1 = d0 + 8;
    const char* vsrc0 = vtg_h + (size_t)d0 * 4096 + c8 * 16;
    const char* vsrc1 = vtg_h + (size_t)d1 * 4096 + c8 * 16;
    // constant swizzled LDS write dests: chunk c8 of row r -> LDS chunk c8^(r&7)
    // K rows w*16+l8 and w*16+8+l8: both (row&7)==l8
    unsigned short* kd0 = &Kl[w * 16 + l8][(c8 ^ l8) * 8];
    unsigned short* kd1 = &Kl[w * 16 + 8 + l8][(c8 ^ l8) * 8];
    const int fd0 = (d0 & 7) ^ (d0 >> 3), fd1 = (d1 & 7) ^ (d1 >> 3);
    unsigned short* vd0 = &Vt[d0][(c8 ^ fd0) * 8];
    unsigned short* vd1 = &Vt[d1][(c8 ^ fd1) * 8];

    // bias for the LAST tile only (full tiles all-valid by compaction)
    if (tid < 64) biasf[tid] = ((nt - 1) * 64 + tid < nc) ? 0.0f : -1e9f;

    // prologue: tile 0 into regs
    uint4 k0r = *(const uint4*)ksrc;
    uint4 k1r = *(const uint4*)(ksrc + 8 * 2048);
    uint4 v0r = *(const uint4*)vsrc0;
    uint4 v1r = *(const uint4*)vsrc1;
    ksrc += TSK; vsrc0 += 128; vsrc1 += 128;

    for (int t = 0; t < nt; ++t) {
        __syncthreads();          // A: prior tile's LDS reads done (drains vmem)
        *(uint4*)kd0 = k0r;
        *(uint4*)kd1 = k1r;
        *(uint4*)vd0 = v0r;
        *(uint4*)vd1 = v1r;
        __syncthreads();          // B: lgkm drain, tiles visible (no vmem pending)

        // T14: issue tile t+1's loads now; they land during compute below
        if (t + 1 < nt) {
            k0r = *(const uint4*)ksrc;
            k1r = *(const uint4*)(ksrc + 8 * 2048);
            v0r = *(const uint4*)vsrc0;
            v1r = *(const uint4*)vsrc1;
            ksrc += TSK; vsrc0 += 128; vsrc1 += 128;
        }

        // K fragments
        sh8 kf[4][2];
#pragma unroll
        for (int tt = 0; tt < 4; ++tt) {
            const unsigned short* kp = &Kl[tt * 16 + fr][0];
#pragma unroll
            for (int c = 0; c < 2; ++c)
                kf[tt][c] = *(const sh8*)&kp[((4 * c + hi) ^ (fr & 7)) * 8];
        }

        // S^T = K Q
        f32x4 s[4] = {};
        __builtin_amdgcn_s_setprio(1);
#pragma unroll
        for (int tt = 0; tt < 4; ++tt) {
            s[tt] = MFMA16(kf[tt][0], qf0, s[tt]);
            s[tt] = MFMA16(kf[tt][1], qf1, s[tt]);
        }
        __builtin_amdgcn_s_setprio(0);

        if (t == nt - 1) {                // mask bias: last tile only
#pragma unroll
            for (int tt = 0; tt < 4; ++tt)
                s[tt] += *(const f32x4*)&biasf[tt * 16 + 4 * hi];
        }

        float pm = s[0][0];
#pragma unroll
        for (int tt = 0; tt < 4; ++tt)
#pragma unroll
            for (int r = 0; r < 4; ++r) pm = fmaxf(pm, s[tt][r]);
        pm = redmax_hi(pm);

        if (!__all(pm <= mrow)) {           // defer-max: wave-uniform skip
            float mn = fmaxf(mrow, pm);
            float scl = __builtin_amdgcn_exp2f(mrow - mn);
            lrow *= scl;
#pragma unroll
            for (int df = 0; df < 4; ++df) acc[df] *= scl;
            mrow = mn;
        }

        float ps = 0.f;
#pragma unroll
        for (int tt = 0; tt < 4; ++tt)
#pragma unroll
            for (int r = 0; r < 4; ++r) {
                float p = __builtin_amdgcn_exp2f(s[tt][r] - mrow);
                s[tt][r] = p;
                ps += p;
            }
        lrow += redsum_hi(ps);

        // P -> per-wave LDS (4x b64)
#pragma unroll
        for (int tt = 0; tt < 4; ++tt) {
            uint2 pw = { pack2bf(s[tt][0], s[tt][1]), pack2bf(s[tt][2], s[tt][3]) };
            *(uint2*)&Pl[w][fr][tt * 16 + hi * 4] = pw;
        }

        // O^T += V^T * P
#pragma unroll
        for (int c = 0; c < 2; ++c) {
            sh8 pa = *(const sh8*)&Pl[w][fr][c * 32 + hi * 8];
            __builtin_amdgcn_s_setprio(1);
#pragma unroll
            for (int df = 0; df < 4; ++df) {
                int d = df * 16 + fr;
                int fd = (d & 7) ^ (d >> 3);
                sh8 vfr = *(const sh8*)&Vt[d][((4 * c + hi) ^ fd) * 8];
                acc[df] = MFMA16(vfr, pa, acc[df]);
            }
            __builtin_amdgcn_s_setprio(0);
        }
    }

    {
        float inv = 1.0f / lrow;
        long qr = base + q0 + w * 16 + fr;
        unsigned short* op = &ao[qr * 1024 + h * 64];
#pragma unroll
        for (int df = 0; df < 4; ++df) {
            f32x4 o = acc[df];
            uint2 ow = { pack2bf(o[0] * inv, o[1] * inv), pack2bf(o[2] * inv, o[3] * inv) };
            *(uint2*)&op[df * 16 + hi * 4] = ow;
        }
    }
}

// ---------------------------------------------------------------------------
// Output projection, m97-style staging (unchanged).
// ---------------------------------------------------------------------------
__global__ __launch_bounds__(256) void gemm_out_k(
    const unsigned short* __restrict__ ao, const unsigned short* __restrict__ wob,
    const float* __restrict__ bo, float* __restrict__ out)
{
    __shared__ unsigned short As[128][32];
    __shared__ unsigned short Bs[128][32];
    const int tid = threadIdx.x;
    const int l = tid & 63, w = tid >> 6;
    const int wr = w >> 1, wc = w & 1;
    const long row0 = (long)blockIdx.y * 128;
    const int col0 = blockIdx.x * 128;

    f32x4 acc[4][4] = {};
    const int fr = l & 15, hi = l >> 4;

    const int sr = tid >> 2;
    const int sc = (tid & 3) * 8;
    const unsigned short* ga = &ao[(row0 + sr) * 1024 + sc];
    const unsigned short* gb = &wob[(long)(col0 + sr) * 1024 + sc];
    unsigned short* la = &As[w * 16][0];
    unsigned short* lb = &Bs[w * 16][0];

    for (int k0 = 0; k0 < 1024; k0 += 32) {
        __syncthreads();
        gload_lds16(ga + k0, la);
        gload_lds16(ga + 64 * 1024 + k0, la + 64 * 32);
        gload_lds16(gb + k0, lb);
        gload_lds16(gb + 64 * 1024 + k0, lb + 64 * 32);
        __syncthreads();

        sh8 af[4], bf[4];
#pragma unroll
        for (int i = 0; i < 4; ++i) {
            af[i] = *(const sh8*)&As[wr * 64 + i * 16 + fr][hi * 8];
            bf[i] = *(const sh8*)&Bs[wc * 64 + i * 16 + fr][hi * 8];
        }
#pragma unroll
        for (int i = 0; i < 4; ++i)
#pragma unroll
            for (int j = 0; j < 4; ++j)
                acc[i][j] = MFMA16(af[i], bf[j], acc[i][j]);
    }

    const int rg = hi * 4, cg = l & 15;
#pragma unroll
    for (int i = 0; i < 4; ++i)
#pragma unroll
        for (int j = 0; j < 4; ++j) {
            long gr = row0 + wr * 64 + i * 16 + rg;
            int gc = col0 + wc * 64 + j * 16 + cg;
            float bb = bo[gc];
#pragma unroll
            for (int r = 0; r < 4; ++r)
                out[(gr + r) * 1024 + gc] = acc[i][j][r] + bb;
        }
}

extern "C" void kernel_launch(void* const* d_in, const int* in_sizes, int n_in,
                              void* d_out, int out_size, void* d_ws, size_t ws_size,
                              hipStream_t stream) {
    const float* x    = (const float*)d_in[0];
    const int*   mask = (const int*)d_in[1];
    const float* Wq   = (const float*)d_in[2];
    const float* Wk   = (const float*)d_in[3];
    const float* Wv   = (const float*)d_in[4];
    const float* Wo   = (const float*)d_in[5];
    const float* bo   = (const float*)d_in[6];
    float* out = (float*)d_out;

    const size_t wbf_bytes = (size_t)4096 * 1024 * 2;              // 8 MiB
    const size_t idx_bytes = (size_t)4 * 2048 * 4 + 64;
    const size_t xbf_per_b = (size_t)2048 * 1024 * 2;              // 4 MiB
    const size_t qkv_per_b = (size_t)2048 * 3072 * 2;              // 12 MiB
    const size_t ao_per_b  = (size_t)2048 * 1024 * 2;              // 4 MiB
    const size_t kck_per_b = (size_t)2048 * 1024 * 2;              // 4 MiB
    const size_t vt_per_b  = (size_t)16 * 64 * 2048 * 2;           // 4 MiB
    const size_t per_b = xbf_per_b + qkv_per_b + ao_per_b + kck_per_b + vt_per_b; // 28 MiB

    size_t fixed = wbf_bytes + idx_bytes;
    size_t avail = (ws_size > fixed) ? (ws_size - fixed) : 0;
    int bchunk = (avail >= per_b) ? (int)(avail / per_b) : 1;
    if (bchunk > 4) bchunk = 4;

    char* p = (char*)d_ws;
    unsigned short* wbf = (unsigned short*)p;            p += wbf_bytes;
    int* idxp = (int*)p;                                 p += (size_t)4 * 2048 * 4;
    int* cntp = (int*)p;                                 p += 64;
    unsigned short* xbf = (unsigned short*)p;            p += (size_t)bchunk * xbf_per_b;
    unsigned short* qkv = (unsigned short*)p;            p += (size_t)bchunk * qkv_per_b;
    unsigned short* ao  = (unsigned short*)p;            p += (size_t)bchunk * ao_per_b;
    unsigned short* Kck = (unsigned short*)p;            p += (size_t)bchunk * kck_per_b;
    unsigned short* Vtg = (unsigned short*)p;

    cvt_w_k<<<4096, 256, 0, stream>>>(Wq, Wk, Wv, Wo, wbf);
    compact_k<<<4, 64, 0, stream>>>(mask, idxp, cntp);

    for (int b0 = 0; b0 < 4; b0 += bchunk) {
        int bc = (4 - b0 < bchunk) ? (4 - b0) : bchunk;
        cvt_x_k<<<2048, 256, 0, stream>>>(
            x + (size_t)b0 * 2048 * 1024, xbf, bc * 524288);
        gemm_qkv_k<<<dim3(24, bc * 16), 256, 0, stream>>>(xbf, wbf, qkv);
        kvgather_k<<<dim3(8, 32, bc), 256, 0, stream>>>(qkv, idxp, cntp, Kck, b0);
        vtrans_k<<<dim3(16, 16, bc), 256, 0, stream>>>(qkv, idxp, cntp, Vtg, b0);
        attn_k<<<dim3(512 * bc), 256, 0, stream>>>(qkv, Kck, Vtg, cntp, ao, b0);
        gemm_out_k<<<dim3(8, bc * 16), 256, 0, stream>>>(
            ao, wbf + (size_t)3072 * 1024, bo, out + (size_t)b0 * 2048 * 1024);
    }
}

// Round 16
// 211.860 us; speedup vs baseline: 1.0427x; 1.0207x over previous
//
#include <hip/hip_runtime.h>
#include <hip/hip_bf16.h>

typedef __attribute__((ext_vector_type(8))) short sh8;
typedef __attribute__((ext_vector_type(4))) float f32x4;

#define MFMA16(a, b, c) __builtin_amdgcn_mfma_f32_16x16x32_bf16((a), (b), (c), 0, 0, 0)

__device__ __forceinline__ unsigned short f2bf(float f) {
    return (unsigned short)((__float_as_uint(f) + 0x8000u) >> 16);
}
__device__ __forceinline__ unsigned int pack2bf(float lo, float hi) {
    unsigned int ul = __float_as_uint(lo) + 0x8000u;
    unsigned int uh = __float_as_uint(hi) + 0x8000u;
    return __builtin_amdgcn_perm(uh, ul, 0x07060302u);
}
__device__ __forceinline__ float redmax_hi(float x) {
    x = fmaxf(x, __shfl_xor(x, 16, 64));
    return fmaxf(x, __shfl_xor(x, 32, 64));
}
__device__ __forceinline__ float redsum_hi(float x) {
    x += __shfl_xor(x, 16, 64);
    return x + __shfl_xor(x, 32, 64);
}
// async global->LDS, 16B per lane; LDS dest = wave-uniform base + lane*16
__device__ __forceinline__ void gload_lds16(const void* g, void* l) {
    __builtin_amdgcn_global_load_lds(
        (const __attribute__((address_space(1))) unsigned int*)g,
        (__attribute__((address_space(3))) unsigned int*)l, 16, 0, 0);
}

// ---------------------------------------------------------------------------
// f32 -> bf16 converters (run once)
// ---------------------------------------------------------------------------
__global__ __launch_bounds__(256) void cvt_x_k(
    const float* __restrict__ src, unsigned short* __restrict__ dst, int n4)
{
    int i = blockIdx.x * 256 + threadIdx.x;
    int stride = gridDim.x * 256;
    for (; i < n4; i += stride) {
        float4 v = ((const float4*)src)[i];
        uint2 h = { pack2bf(v.x, v.y), pack2bf(v.z, v.w) };
        ((uint2*)dst)[i] = h;
    }
}
__global__ __launch_bounds__(256) void cvt_w_k(
    const float* __restrict__ Wq, const float* __restrict__ Wk,
    const float* __restrict__ Wv, const float* __restrict__ Wo,
    unsigned short* __restrict__ wbf)
{
    int i = blockIdx.x * 256 + threadIdx.x;   // over 4*262144 float4s
    int seg = i >> 18;
    int off = i & 0x3FFFF;
    const float* s = (seg < 2) ? ((seg == 0) ? Wq : Wk) : ((seg == 2) ? Wv : Wo);
    float4 v = ((const float4*)s)[off];
    uint2 h = { pack2bf(v.x, v.y), pack2bf(v.z, v.w) };
    ((uint2*)wbf)[i] = h;
}

// ---------------------------------------------------------------------------
// Mask compaction: list of kv indices with mask!=0 (exactness: masked kv get
// softmax weight exactly 0 in fp32).
// ---------------------------------------------------------------------------
__global__ __launch_bounds__(64) void compact_k(
    const int* __restrict__ mask, int* __restrict__ idx, int* __restrict__ cnt)
{
    const int b = blockIdx.x, l = threadIdx.x;
    const int* mb = mask + b * 2048;
    int base = 0;
    for (int i = 0; i < 32; ++i) {
        int m = mb[i * 64 + l];
        unsigned long long bal = __ballot(m != 0);
        int pre = __popcll(bal & ((1ull << l) - 1ull));
        if (m) idx[b * 2048 + base + pre] = i * 64 + l;
        base += (int)__popcll(bal);
    }
    if (base == 0) {
        for (int i = l; i < 2048; i += 64) idx[b * 2048 + i] = i;
        base = 2048;
    }
    if (l == 0) cnt[b] = base;
}

// ---------------------------------------------------------------------------
// R16: gather compacted x rows -> xc[b][row][1024] (bf16). K/V projections
// are then computed ONLY for unmasked rows (~half the GEMM work).
// ---------------------------------------------------------------------------
__global__ __launch_bounds__(256) void xgather_k(
    const unsigned short* __restrict__ xbf, const int* __restrict__ idx,
    const int* __restrict__ cnt, unsigned short* __restrict__ xc, int b0)
{
    const int b = blockIdx.z;
    const int t = blockIdx.y;          // tile of 64 rows
    const int z = blockIdx.x;          // row octet 0..7
    const int nc = cnt[b0 + b];
    if (t * 64 >= ((nc + 63) & ~63)) return;
    const int* idxb = idx + (size_t)(b0 + b) * 2048;
    const int tid = threadIdx.x;
#pragma unroll
    for (int p = 0; p < 4; ++p) {
        int i = p * 256 + tid;                 // 0..1023
        int r = t * 64 + z * 8 + (i >> 7);
        int c = i & 127;
        int src = idxb[min(r, nc - 1)];
        uint4 v = *(const uint4*)&xbf[((size_t)b * 2048 + src) * 1024 + c * 8];
        *(uint4*)&xc[((size_t)b * 2048 + r) * 1024 + c * 8] = v;
    }
}

// ---------------------------------------------------------------------------
// R16 fused projection (m97-style staging). 24 col-blocks:
//   bx 0-7  : Q = x @ Wq^T for ALL rows -> qb (scaled by log2(e)/8)
//   bx 8-15 : K = xc @ Wk^T for COMPACTED rows -> Kck (dense, stride 1024)
//   bx 16-23: V = xc @ Wv^T for COMPACTED rows -> written TRANSPOSED into
//             Vtg[b*16+h][d][kv] straight from the epilogue (kv = row is the
//             accumulator's r axis -> 4 values pack to one 8B store).
// Replaces gemm_qkv + kvgather + vtrans (K/V work halves via compaction).
// ---------------------------------------------------------------------------
__global__ __launch_bounds__(256) void gemm_proj_k(
    const unsigned short* __restrict__ xbf, const unsigned short* __restrict__ xc,
    const unsigned short* __restrict__ wbf, const int* __restrict__ cnt, int b0,
    unsigned short* __restrict__ qb, unsigned short* __restrict__ Kck,
    unsigned short* __restrict__ Vtg)
{
    __shared__ unsigned short As[128][32];
    __shared__ unsigned short Bs[128][32];
    const int tid = threadIdx.x;
    const int l = tid & 63, w = tid >> 6;
    const int wr = w >> 1, wc = w & 1;
    const int bx = blockIdx.x;                 // 0..23
    const int bl = blockIdx.y >> 4;            // chunk-local batch
    const int rl = (blockIdx.y & 15) * 128;    // local row
    const int mode = (bx < 8) ? 0 : ((bx < 16) ? 1 : 2);  // Q, K, V

    if (mode != 0) {
        int ncp = (cnt[b0 + bl] + 63) & ~63;
        if (rl >= ncp) return;                 // whole block exits: safe
    }
    const long row0 = (long)bl * 2048 + rl;
    const unsigned short* Asrc = (mode == 0) ? xbf : xc;
    const int wrow0 = (mode == 0) ? bx * 128 : (1024 + (bx - 8) * 128);

    f32x4 acc[4][4] = {};
    const int fr = l & 15, hi = l >> 4;

    const int sr = tid >> 2;
    const int sc = (tid & 3) * 8;
    const unsigned short* ga = &Asrc[(row0 + sr) * 1024 + sc];
    const unsigned short* gb = &wbf[(long)(wrow0 + sr) * 1024 + sc];
    unsigned short* la = &As[w * 16][0];
    unsigned short* lb = &Bs[w * 16][0];

    for (int k0 = 0; k0 < 1024; k0 += 32) {
        __syncthreads();
        gload_lds16(ga + k0, la);
        gload_lds16(ga + 64 * 1024 + k0, la + 64 * 32);
        gload_lds16(gb + k0, lb);
        gload_lds16(gb + 64 * 1024 + k0, lb + 64 * 32);
        __syncthreads();

        sh8 af[4], bf[4];
#pragma unroll
        for (int i = 0; i < 4; ++i) {
            af[i] = *(const sh8*)&As[wr * 64 + i * 16 + fr][hi * 8];
            bf[i] = *(const sh8*)&Bs[wc * 64 + i * 16 + fr][hi * 8];
        }
#pragma unroll
        for (int i = 0; i < 4; ++i)
#pragma unroll
            for (int j = 0; j < 4; ++j)
                acc[i][j] = MFMA16(af[i], bf[j], acc[i][j]);
    }

    const int rg = hi * 4, cg = l & 15;
    if (mode == 2) {
        // V transposed write: feat in [0,1024) over V's 16 heads x 64 dims
#pragma unroll
        for (int i = 0; i < 4; ++i)
#pragma unroll
            for (int j = 0; j < 4; ++j) {
                int feat = (bx - 8) * 128 + wc * 64 + j * 16 + cg - 1024;
                int hh = feat >> 6, dd = feat & 63;
                long kv = rl + wr * 64 + i * 16 + rg;      // local kv (r=0..3 follow)
                unsigned short* vt = Vtg + ((size_t)(bl * 16 + hh) * 64 + dd) * 2048 + kv;
                uint2 ow = { pack2bf(acc[i][j][0], acc[i][j][1]),
                             pack2bf(acc[i][j][2], acc[i][j][3]) };
                *(uint2*)vt = ow;
            }
    } else {
        unsigned short* outp = (mode == 0) ? qb : Kck;
        const float scale = (mode == 0) ? 0.1803368801f : 1.0f;  // log2(e)/8
        const int c0 = (mode == 0) ? bx * 128 : (bx - 8) * 128;
#pragma unroll
        for (int i = 0; i < 4; ++i)
#pragma unroll
            for (int j = 0; j < 4; ++j) {
                long gr = row0 + wr * 64 + i * 16 + rg;
                int gc = c0 + wc * 64 + j * 16 + cg;
#pragma unroll
                for (int r = 0; r < 4; ++r)
                    outp[(gr + r) * 1024 + gc] = f2bf(acc[i][j][r] * scale);
            }
    }
}

// ---------------------------------------------------------------------------
// Flash attention = R12 verbatim (best measured: 86.3us, VGPR 64, occ 36%)
// except Q is read from qb (stride 1024). K from Kck (stride 2048B), V from
// Vtg; both staged via global_load_lds with source-side XOR swizzle. Mask
// bias applied only on the LAST tile (full tiles all-valid by compaction).
// R13 (2 q-groups), R14 (LDS dbuf), R15 (reg-staged T14) all regressed:
// occupancy is the governing resource for this kernel.
// ---------------------------------------------------------------------------
__global__ __launch_bounds__(256) void attn_k(
    const unsigned short* __restrict__ qb, const unsigned short* __restrict__ Kck,
    const unsigned short* __restrict__ Vtg, const int* __restrict__ cnt,
    unsigned short* __restrict__ ao, int b0)
{
    __shared__ unsigned short Kl[64][64];
    __shared__ unsigned short Vt[64][64];
    __shared__ float biasf[64];
    __shared__ unsigned short Pl[4][16][72];

    const int tid = threadIdx.x;
    const int l = tid & 63, w = tid >> 6;
    const int fr = l & 15, hi = l >> 4;

    // T1: bijective XCD swizzle
    int nwg = gridDim.x;
    int wgid = ((nwg & 7) == 0) ? ((blockIdx.x & 7) * (nwg >> 3) + (blockIdx.x >> 3))
                                : blockIdx.x;
    const int qb_ = wgid & 31;
    const int h  = (wgid >> 5) & 15;
    const int b  = wgid >> 9;
    const int q0 = qb_ * 64;
    const long base = (long)b * 2048;

    const int nc = cnt[b0 + b];
    const int nt = (nc + 63) >> 6;

    sh8 qf0, qf1;
    {
        const unsigned short* qp = &qb[(base + q0 + w * 16 + fr) * 1024 + h * 64 + hi * 8];
        qf0 = *(const sh8*)qp;
        qf1 = *(const sh8*)(qp + 32);
    }

    f32x4 acc[4] = {};
    float mrow = -1e30f;
    float lrow = 0.f;

    const long TSK = 131072;                      // 64 rows * 2048 B per K tile
    const char* kck_b = (const char*)Kck + (size_t)b * 2048 * 2048;

    // K gload: lane covers LDS slot (row8 = l>>3, chunk = l&7); source chunk
    // = (l&7)^(l>>3) so LDS holds content chunk c' = global chunk c'^(r&7).
    const int l8 = l >> 3, c8 = l & 7;
    const char* ksrc = kck_b + (size_t)(w * 16 + l8) * 2048 + h * 128 + ((c8 ^ l8) * 16);
    unsigned short* kdst0 = &Kl[w * 16][0];
    unsigned short* kdst1 = &Kl[w * 16 + 8][0];

    // V gload from transposed Vtg: wave w stages d rows w*16..w*16+15;
    // source chunk pre-swizzled by fd = (d&7)^(d>>3).
    const char* vtg_h = (const char*)Vtg + ((size_t)b * 16 + h) * 64 * 4096;
    const int d0 = w * 16 + l8, d1 = d0 + 8;
    const int fd0 = (d0 & 7) ^ (d0 >> 3), fd1 = (d1 & 7) ^ (d1 >> 3);
    const char* vsrc0 = vtg_h + (size_t)d0 * 4096 + ((c8 ^ fd0) * 16);
    const char* vsrc1 = vtg_h + (size_t)d1 * 4096 + ((c8 ^ fd1) * 16);
    unsigned short* vdst0 = &Vt[w * 16][0];
    unsigned short* vdst1 = &Vt[w * 16 + 8][0];

    // bias for the LAST tile only (full tiles all-valid by compaction)
    if (tid < 64) biasf[tid] = ((nt - 1) * 64 + tid < nc) ? 0.0f : -1e9f;

    for (int t = 0; t < nt; ++t) {
        __syncthreads();                  // prior tile's LDS reads done
        gload_lds16(ksrc, kdst0);
        gload_lds16(ksrc + 8 * 2048, kdst1);
        ksrc += TSK;
        gload_lds16(vsrc0, vdst0);
        gload_lds16(vsrc1, vdst1);
        vsrc0 += 128; vsrc1 += 128;
        __syncthreads();                  // vmcnt drained: tiles resident

        // K fragments
        sh8 kf[4][2];
#pragma unroll
        for (int tt = 0; tt < 4; ++tt) {
            const unsigned short* kp = &Kl[tt * 16 + fr][0];
#pragma unroll
            for (int c = 0; c < 2; ++c)
                kf[tt][c] = *(const sh8*)&kp[((4 * c + hi) ^ (fr & 7)) * 8];
        }

        // S^T = K Q
        f32x4 s[4] = {};
        __builtin_amdgcn_s_setprio(1);
#pragma unroll
        for (int tt = 0; tt < 4; ++tt) {
            s[tt] = MFMA16(kf[tt][0], qf0, s[tt]);
            s[tt] = MFMA16(kf[tt][1], qf1, s[tt]);
        }
        __builtin_amdgcn_s_setprio(0);

        if (t == nt - 1) {                // mask bias: last tile only
#pragma unroll
            for (int tt = 0; tt < 4; ++tt)
                s[tt] += *(const f32x4*)&biasf[tt * 16 + 4 * hi];
        }

        float pm = s[0][0];
#pragma unroll
        for (int tt = 0; tt < 4; ++tt)
#pragma unroll
            for (int r = 0; r < 4; ++r) pm = fmaxf(pm, s[tt][r]);
        pm = redmax_hi(pm);

        if (!__all(pm <= mrow)) {           // defer-max: wave-uniform skip
            float mn = fmaxf(mrow, pm);
            float scl = __builtin_amdgcn_exp2f(mrow - mn);
            lrow *= scl;
#pragma unroll
            for (int df = 0; df < 4; ++df) acc[df] *= scl;
            mrow = mn;
        }

        float ps = 0.f;
#pragma unroll
        for (int tt = 0; tt < 4; ++tt)
#pragma unroll
            for (int r = 0; r < 4; ++r) {
                float p = __builtin_amdgcn_exp2f(s[tt][r] - mrow);
                s[tt][r] = p;
                ps += p;
            }
        lrow += redsum_hi(ps);

        // P -> per-wave LDS (4x b64)
#pragma unroll
        for (int tt = 0; tt < 4; ++tt) {
            uint2 pw = { pack2bf(s[tt][0], s[tt][1]), pack2bf(s[tt][2], s[tt][3]) };
            *(uint2*)&Pl[w][fr][tt * 16 + hi * 4] = pw;
        }

        // O^T += V^T * P
#pragma unroll
        for (int c = 0; c < 2; ++c) {
            sh8 pa = *(const sh8*)&Pl[w][fr][c * 32 + hi * 8];
            __builtin_amdgcn_s_setprio(1);
#pragma unroll
            for (int df = 0; df < 4; ++df) {
                int d = df * 16 + fr;
                int fd = (d & 7) ^ (d >> 3);
                sh8 vfr = *(const sh8*)&Vt[d][((4 * c + hi) ^ fd) * 8];
                acc[df] = MFMA16(vfr, pa, acc[df]);
            }
            __builtin_amdgcn_s_setprio(0);
        }
    }

    {
        float inv = 1.0f / lrow;
        long qr = base + q0 + w * 16 + fr;
        unsigned short* op = &ao[qr * 1024 + h * 64];
#pragma unroll
        for (int df = 0; df < 4; ++df) {
            f32x4 o = acc[df];
            uint2 ow = { pack2bf(o[0] * inv, o[1] * inv), pack2bf(o[2] * inv, o[3] * inv) };
            *(uint2*)&op[df * 16 + hi * 4] = ow;
        }
    }
}

// ---------------------------------------------------------------------------
// Output projection, m97-style staging (unchanged).
// ---------------------------------------------------------------------------
__global__ __launch_bounds__(256) void gemm_out_k(
    const unsigned short* __restrict__ ao, const unsigned short* __restrict__ wob,
    const float* __restrict__ bo, float* __restrict__ out)
{
    __shared__ unsigned short As[128][32];
    __shared__ unsigned short Bs[128][32];
    const int tid = threadIdx.x;
    const int l = tid & 63, w = tid >> 6;
    const int wr = w >> 1, wc = w & 1;
    const long row0 = (long)blockIdx.y * 128;
    const int col0 = blockIdx.x * 128;

    f32x4 acc[4][4] = {};
    const int fr = l & 15, hi = l >> 4;

    const int sr = tid >> 2;
    const int sc = (tid & 3) * 8;
    const unsigned short* ga = &ao[(row0 + sr) * 1024 + sc];
    const unsigned short* gb = &wob[(long)(col0 + sr) * 1024 + sc];
    unsigned short* la = &As[w * 16][0];
    unsigned short* lb = &Bs[w * 16][0];

    for (int k0 = 0; k0 < 1024; k0 += 32) {
        __syncthreads();
        gload_lds16(ga + k0, la);
        gload_lds16(ga + 64 * 1024 + k0, la + 64 * 32);
        gload_lds16(gb + k0, lb);
        gload_lds16(gb + 64 * 1024 + k0, lb + 64 * 32);
        __syncthreads();

        sh8 af[4], bf[4];
#pragma unroll
        for (int i = 0; i < 4; ++i) {
            af[i] = *(const sh8*)&As[wr * 64 + i * 16 + fr][hi * 8];
            bf[i] = *(const sh8*)&Bs[wc * 64 + i * 16 + fr][hi * 8];
        }
#pragma unroll
        for (int i = 0; i < 4; ++i)
#pragma unroll
            for (int j = 0; j < 4; ++j)
                acc[i][j] = MFMA16(af[i], bf[j], acc[i][j]);
    }

    const int rg = hi * 4, cg = l & 15;
#pragma unroll
    for (int i = 0; i < 4; ++i)
#pragma unroll
        for (int j = 0; j < 4; ++j) {
            long gr = row0 + wr * 64 + i * 16 + rg;
            int gc = col0 + wc * 64 + j * 16 + cg;
            float bb = bo[gc];
#pragma unroll
            for (int r = 0; r < 4; ++r)
                out[(gr + r) * 1024 + gc] = acc[i][j][r] + bb;
        }
}

extern "C" void kernel_launch(void* const* d_in, const int* in_sizes, int n_in,
                              void* d_out, int out_size, void* d_ws, size_t ws_size,
                              hipStream_t stream) {
    const float* x    = (const float*)d_in[0];
    const int*   mask = (const int*)d_in[1];
    const float* Wq   = (const float*)d_in[2];
    const float* Wk   = (const float*)d_in[3];
    const float* Wv   = (const float*)d_in[4];
    const float* Wo   = (const float*)d_in[5];
    const float* bo   = (const float*)d_in[6];
    float* out = (float*)d_out;

    const size_t wbf_bytes = (size_t)4096 * 1024 * 2;              // 8 MiB
    const size_t idx_bytes = (size_t)4 * 2048 * 4 + 64;
    const size_t seg_b = (size_t)2048 * 1024 * 2;                  // 4 MiB
    // per batch: xbf + xc + qb + Kck + Vtg + ao = 6 segments = 24 MiB
    const size_t per_b = 6 * seg_b;

    size_t fixed = wbf_bytes + idx_bytes;
    size_t avail = (ws_size > fixed) ? (ws_size - fixed) : 0;
    int bchunk = (avail >= per_b) ? (int)(avail / per_b) : 1;
    if (bchunk > 4) bchunk = 4;

    char* p = (char*)d_ws;
    unsigned short* wbf = (unsigned short*)p;            p += wbf_bytes;
    int* idxp = (int*)p;                                 p += (size_t)4 * 2048 * 4;
    int* cntp = (int*)p;                                 p += 64;
    unsigned short* xbf = (unsigned short*)p;            p += (size_t)bchunk * seg_b;
    unsigned short* xc  = (unsigned short*)p;            p += (size_t)bchunk * seg_b;
    unsigned short* qbp = (unsigned short*)p;            p += (size_t)bchunk * seg_b;
    unsigned short* Kck = (unsigned short*)p;            p += (size_t)bchunk * seg_b;
    unsigned short* Vtg = (unsigned short*)p;            p += (size_t)bchunk * seg_b;
    unsigned short* ao  = (unsigned short*)p;

    cvt_w_k<<<4096, 256, 0, stream>>>(Wq, Wk, Wv, Wo, wbf);
    compact_k<<<4, 64, 0, stream>>>(mask, idxp, cntp);

    for (int b0 = 0; b0 < 4; b0 += bchunk) {
        int bc = (4 - b0 < bchunk) ? (4 - b0) : bchunk;
        cvt_x_k<<<2048, 256, 0, stream>>>(
            x + (size_t)b0 * 2048 * 1024, xbf, bc * 524288);
        xgather_k<<<dim3(8, 32, bc), 256, 0, stream>>>(xbf, idxp, cntp, xc, b0);
        gemm_proj_k<<<dim3(24, 16 * bc), 256, 0, stream>>>(
            xbf, xc, wbf, cntp, b0, qbp, Kck, Vtg);
        attn_k<<<dim3(512 * bc), 256, 0, stream>>>(qbp, Kck, Vtg, cntp, ao, b0);
        gemm_out_k<<<dim3(8, bc * 16), 256, 0, stream>>>(
            ao, wbf + (size_t)3072 * 1024, bo, out + (size_t)b0 * 2048 * 1024);
    }
}

// Round 17
// 205.750 us; speedup vs baseline: 1.0737x; 1.0297x over previous
//
#include <hip/hip_runtime.h>
#include <hip/hip_bf16.h>

typedef __attribute__((ext_vector_type(8))) short sh8;
typedef __attribute__((ext_vector_type(4))) float f32x4;

#define MFMA16(a, b, c) __builtin_amdgcn_mfma_f32_16x16x32_bf16((a), (b), (c), 0, 0, 0)

__device__ __forceinline__ unsigned short f2bf(float f) {
    return (unsigned short)((__float_as_uint(f) + 0x8000u) >> 16);
}
__device__ __forceinline__ unsigned int pack2bf(float lo, float hi) {
    unsigned int ul = __float_as_uint(lo) + 0x8000u;
    unsigned int uh = __float_as_uint(hi) + 0x8000u;
    return __builtin_amdgcn_perm(uh, ul, 0x07060302u);
}
__device__ __forceinline__ float redmax_hi(float x) {
    x = fmaxf(x, __shfl_xor(x, 16, 64));
    return fmaxf(x, __shfl_xor(x, 32, 64));
}
__device__ __forceinline__ float redsum_hi(float x) {
    x += __shfl_xor(x, 16, 64);
    return x + __shfl_xor(x, 32, 64);
}
// async global->LDS, 16B per lane; LDS dest = wave-uniform base + lane*16
__device__ __forceinline__ void gload_lds16(const void* g, void* l) {
    __builtin_amdgcn_global_load_lds(
        (const __attribute__((address_space(1))) unsigned int*)g,
        (__attribute__((address_space(3))) unsigned int*)l, 16, 0, 0);
}

// ---------------------------------------------------------------------------
// R17 fused prep: three independent jobs partitioned by blockIdx range.
//   blocks [0, 4096)        : Wq|Wk|Wv|Wo (f32) -> wbf[4096][1024] bf16
//   blocks [4096, 4100)     : mask compaction (wave 0 of each block)
//   blocks [4100, 4100+2048): x (f32, current chunk) -> xbf bf16, grid-stride
// Saves 2 launch gaps; bodies identical to R16's cvt_w_k/compact_k/cvt_x_k.
// ---------------------------------------------------------------------------
__global__ __launch_bounds__(256) void prep_k(
    const float* __restrict__ x, const float* __restrict__ Wq,
    const float* __restrict__ Wk, const float* __restrict__ Wv,
    const float* __restrict__ Wo, const int* __restrict__ mask,
    unsigned short* __restrict__ wbf, unsigned short* __restrict__ xbf,
    int* __restrict__ idx, int* __restrict__ cnt, int nx4)
{
    const int bid = blockIdx.x;
    if (bid < 4096) {
        // cvt_w: 4096 blocks x 256 threads x 1 float4
        int i = bid * 256 + threadIdx.x;
        int seg = i >> 18;
        int off = i & 0x3FFFF;
        const float* s = (seg < 2) ? ((seg == 0) ? Wq : Wk) : ((seg == 2) ? Wv : Wo);
        float4 v = ((const float4*)s)[off];
        uint2 h = { pack2bf(v.x, v.y), pack2bf(v.z, v.w) };
        ((uint2*)wbf)[i] = h;
    } else if (bid < 4100) {
        // compaction: one wave per batch
        if (threadIdx.x < 64) {
            const int b = bid - 4096, l = threadIdx.x;
            const int* mb = mask + b * 2048;
            int base = 0;
            for (int i = 0; i < 32; ++i) {
                int m = mb[i * 64 + l];
                unsigned long long bal = __ballot(m != 0);
                int pre = __popcll(bal & ((1ull << l) - 1ull));
                if (m) idx[b * 2048 + base + pre] = i * 64 + l;
                base += (int)__popcll(bal);
            }
            if (base == 0) {
                for (int i = l; i < 2048; i += 64) idx[b * 2048 + i] = i;
                base = 2048;
            }
            if (l == 0) cnt[b] = base;
        }
    } else {
        // cvt_x: grid-stride over the current chunk's float4s
        int i = (bid - 4100) * 256 + threadIdx.x;
        int stride = (gridDim.x - 4100) * 256;
        for (; i < nx4; i += stride) {
            float4 v = ((const float4*)x)[i];
            uint2 h = { pack2bf(v.x, v.y), pack2bf(v.z, v.w) };
            ((uint2*)xbf)[i] = h;
        }
    }
}

// ---------------------------------------------------------------------------
// Gather compacted x rows -> xc[b][row][1024] (bf16). K/V projections are
// computed ONLY for unmasked rows (~half the GEMM work).
// ---------------------------------------------------------------------------
__global__ __launch_bounds__(256) void xgather_k(
    const unsigned short* __restrict__ xbf, const int* __restrict__ idx,
    const int* __restrict__ cnt, unsigned short* __restrict__ xc, int b0)
{
    const int b = blockIdx.z;
    const int t = blockIdx.y;          // tile of 64 rows
    const int z = blockIdx.x;          // row octet 0..7
    const int nc = cnt[b0 + b];
    if (t * 64 >= ((nc + 63) & ~63)) return;
    const int* idxb = idx + (size_t)(b0 + b) * 2048;
    const int tid = threadIdx.x;
#pragma unroll
    for (int p = 0; p < 4; ++p) {
        int i = p * 256 + tid;                 // 0..1023
        int r = t * 64 + z * 8 + (i >> 7);
        int c = i & 127;
        int src = idxb[min(r, nc - 1)];
        uint4 v = *(const uint4*)&xbf[((size_t)b * 2048 + src) * 1024 + c * 8];
        *(uint4*)&xc[((size_t)b * 2048 + r) * 1024 + c * 8] = v;
    }
}

// ---------------------------------------------------------------------------
// Fused projection (m97-style staging). 24 col-blocks:
//   bx 0-7  : Q = x @ Wq^T for ALL rows -> qb (scaled by log2(e)/8)
//   bx 8-15 : K = xc @ Wk^T for COMPACTED rows -> Kck (dense, stride 1024)
//   bx 16-23: V = xc @ Wv^T for COMPACTED rows, written TRANSPOSED into
//             Vtg[b*16+h][d][kv] straight from the epilogue.
// ---------------------------------------------------------------------------
__global__ __launch_bounds__(256) void gemm_proj_k(
    const unsigned short* __restrict__ xbf, const unsigned short* __restrict__ xc,
    const unsigned short* __restrict__ wbf, const int* __restrict__ cnt, int b0,
    unsigned short* __restrict__ qb, unsigned short* __restrict__ Kck,
    unsigned short* __restrict__ Vtg)
{
    __shared__ unsigned short As[128][32];
    __shared__ unsigned short Bs[128][32];
    const int tid = threadIdx.x;
    const int l = tid & 63, w = tid >> 6;
    const int wr = w >> 1, wc = w & 1;
    const int bx = blockIdx.x;                 // 0..23
    const int bl = blockIdx.y >> 4;            // chunk-local batch
    const int rl = (blockIdx.y & 15) * 128;    // local row
    const int mode = (bx < 8) ? 0 : ((bx < 16) ? 1 : 2);  // Q, K, V

    if (mode != 0) {
        int ncp = (cnt[b0 + bl] + 63) & ~63;
        if (rl >= ncp) return;                 // whole block exits: safe
    }
    const long row0 = (long)bl * 2048 + rl;
    const unsigned short* Asrc = (mode == 0) ? xbf : xc;
    const int wrow0 = (mode == 0) ? bx * 128 : (1024 + (bx - 8) * 128);

    f32x4 acc[4][4] = {};
    const int fr = l & 15, hi = l >> 4;

    const int sr = tid >> 2;
    const int sc = (tid & 3) * 8;
    const unsigned short* ga = &Asrc[(row0 + sr) * 1024 + sc];
    const unsigned short* gb = &wbf[(long)(wrow0 + sr) * 1024 + sc];
    unsigned short* la = &As[w * 16][0];
    unsigned short* lb = &Bs[w * 16][0];

    for (int k0 = 0; k0 < 1024; k0 += 32) {
        __syncthreads();
        gload_lds16(ga + k0, la);
        gload_lds16(ga + 64 * 1024 + k0, la + 64 * 32);
        gload_lds16(gb + k0, lb);
        gload_lds16(gb + 64 * 1024 + k0, lb + 64 * 32);
        __syncthreads();

        sh8 af[4], bf[4];
#pragma unroll
        for (int i = 0; i < 4; ++i) {
            af[i] = *(const sh8*)&As[wr * 64 + i * 16 + fr][hi * 8];
            bf[i] = *(const sh8*)&Bs[wc * 64 + i * 16 + fr][hi * 8];
        }
#pragma unroll
        for (int i = 0; i < 4; ++i)
#pragma unroll
            for (int j = 0; j < 4; ++j)
                acc[i][j] = MFMA16(af[i], bf[j], acc[i][j]);
    }

    const int rg = hi * 4, cg = l & 15;
    if (mode == 2) {
        // V transposed write: feat in [0,1024) over V's 16 heads x 64 dims
#pragma unroll
        for (int i = 0; i < 4; ++i)
#pragma unroll
            for (int j = 0; j < 4; ++j) {
                int feat = (bx - 8) * 128 + wc * 64 + j * 16 + cg - 1024;
                int hh = feat >> 6, dd = feat & 63;
                long kv = rl + wr * 64 + i * 16 + rg;      // local kv (r=0..3 follow)
                unsigned short* vt = Vtg + ((size_t)(bl * 16 + hh) * 64 + dd) * 2048 + kv;
                uint2 ow = { pack2bf(acc[i][j][0], acc[i][j][1]),
                             pack2bf(acc[i][j][2], acc[i][j][3]) };
                *(uint2*)vt = ow;
            }
    } else {
        unsigned short* outp = (mode == 0) ? qb : Kck;
        const float scale = (mode == 0) ? 0.1803368801f : 1.0f;  // log2(e)/8
        const int c0 = (mode == 0) ? bx * 128 : (bx - 8) * 128;
#pragma unroll
        for (int i = 0; i < 4; ++i)
#pragma unroll
            for (int j = 0; j < 4; ++j) {
                long gr = row0 + wr * 64 + i * 16 + rg;
                int gc = c0 + wc * 64 + j * 16 + cg;
#pragma unroll
                for (int r = 0; r < 4; ++r)
                    outp[(gr + r) * 1024 + gc] = f2bf(acc[i][j][r] * scale);
            }
    }
}

// ---------------------------------------------------------------------------
// Flash attention (R12/R16 best: 86us, VGPR 64, occ 36%). Q from qb, K from
// Kck, V from Vtg; K/V staged via global_load_lds with source-side XOR
// swizzle; mask bias applied only on the LAST tile (compaction guarantees
// full tiles all-valid). R13/R14/R15 occupancy-trading variants regressed.
// ---------------------------------------------------------------------------
__global__ __launch_bounds__(256) void attn_k(
    const unsigned short* __restrict__ qb, const unsigned short* __restrict__ Kck,
    const unsigned short* __restrict__ Vtg, const int* __restrict__ cnt,
    unsigned short* __restrict__ ao, int b0)
{
    __shared__ unsigned short Kl[64][64];
    __shared__ unsigned short Vt[64][64];
    __shared__ float biasf[64];
    __shared__ unsigned short Pl[4][16][72];

    const int tid = threadIdx.x;
    const int l = tid & 63, w = tid >> 6;
    const int fr = l & 15, hi = l >> 4;

    // T1: bijective XCD swizzle
    int nwg = gridDim.x;
    int wgid = ((nwg & 7) == 0) ? ((blockIdx.x & 7) * (nwg >> 3) + (blockIdx.x >> 3))
                                : blockIdx.x;
    const int qb_ = wgid & 31;
    const int h  = (wgid >> 5) & 15;
    const int b  = wgid >> 9;
    const int q0 = qb_ * 64;
    const long base = (long)b * 2048;

    const int nc = cnt[b0 + b];
    const int nt = (nc + 63) >> 6;

    sh8 qf0, qf1;
    {
        const unsigned short* qp = &qb[(base + q0 + w * 16 + fr) * 1024 + h * 64 + hi * 8];
        qf0 = *(const sh8*)qp;
        qf1 = *(const sh8*)(qp + 32);
    }

    f32x4 acc[4] = {};
    float mrow = -1e30f;
    float lrow = 0.f;

    const long TSK = 131072;                      // 64 rows * 2048 B per K tile
    const char* kck_b = (const char*)Kck + (size_t)b * 2048 * 2048;

    // K gload: lane covers LDS slot (row8 = l>>3, chunk = l&7); source chunk
    // = (l&7)^(l>>3) so LDS holds content chunk c' = global chunk c'^(r&7).
    const int l8 = l >> 3, c8 = l & 7;
    const char* ksrc = kck_b + (size_t)(w * 16 + l8) * 2048 + h * 128 + ((c8 ^ l8) * 16);
    unsigned short* kdst0 = &Kl[w * 16][0];
    unsigned short* kdst1 = &Kl[w * 16 + 8][0];

    // V gload from transposed Vtg: wave w stages d rows w*16..w*16+15;
    // source chunk pre-swizzled by fd = (d&7)^(d>>3).
    const char* vtg_h = (const char*)Vtg + ((size_t)b * 16 + h) * 64 * 4096;
    const int d0 = w * 16 + l8, d1 = d0 + 8;
    const int fd0 = (d0 & 7) ^ (d0 >> 3), fd1 = (d1 & 7) ^ (d1 >> 3);
    const char* vsrc0 = vtg_h + (size_t)d0 * 4096 + ((c8 ^ fd0) * 16);
    const char* vsrc1 = vtg_h + (size_t)d1 * 4096 + ((c8 ^ fd1) * 16);
    unsigned short* vdst0 = &Vt[w * 16][0];
    unsigned short* vdst1 = &Vt[w * 16 + 8][0];

    // bias for the LAST tile only (full tiles all-valid by compaction)
    if (tid < 64) biasf[tid] = ((nt - 1) * 64 + tid < nc) ? 0.0f : -1e9f;

    for (int t = 0; t < nt; ++t) {
        __syncthreads();                  // prior tile's LDS reads done
        gload_lds16(ksrc, kdst0);
        gload_lds16(ksrc + 8 * 2048, kdst1);
        ksrc += TSK;
        gload_lds16(vsrc0, vdst0);
        gload_lds16(vsrc1, vdst1);
        vsrc0 += 128; vsrc1 += 128;
        __syncthreads();                  // vmcnt drained: tiles resident

        // K fragments
        sh8 kf[4][2];
#pragma unroll
        for (int tt = 0; tt < 4; ++tt) {
            const unsigned short* kp = &Kl[tt * 16 + fr][0];
#pragma unroll
            for (int c = 0; c < 2; ++c)
                kf[tt][c] = *(const sh8*)&kp[((4 * c + hi) ^ (fr & 7)) * 8];
        }

        // S^T = K Q
        f32x4 s[4] = {};
        __builtin_amdgcn_s_setprio(1);
#pragma unroll
        for (int tt = 0; tt < 4; ++tt) {
            s[tt] = MFMA16(kf[tt][0], qf0, s[tt]);
            s[tt] = MFMA16(kf[tt][1], qf1, s[tt]);
        }
        __builtin_amdgcn_s_setprio(0);

        if (t == nt - 1) {                // mask bias: last tile only
#pragma unroll
            for (int tt = 0; tt < 4; ++tt)
                s[tt] += *(const f32x4*)&biasf[tt * 16 + 4 * hi];
        }

        float pm = s[0][0];
#pragma unroll
        for (int tt = 0; tt < 4; ++tt)
#pragma unroll
            for (int r = 0; r < 4; ++r) pm = fmaxf(pm, s[tt][r]);
        pm = redmax_hi(pm);

        if (!__all(pm <= mrow)) {           // defer-max: wave-uniform skip
            float mn = fmaxf(mrow, pm);
            float scl = __builtin_amdgcn_exp2f(mrow - mn);
            lrow *= scl;
#pragma unroll
            for (int df = 0; df < 4; ++df) acc[df] *= scl;
            mrow = mn;
        }

        float ps = 0.f;
#pragma unroll
        for (int tt = 0; tt < 4; ++tt)
#pragma unroll
            for (int r = 0; r < 4; ++r) {
                float p = __builtin_amdgcn_exp2f(s[tt][r] - mrow);
                s[tt][r] = p;
                ps += p;
            }
        lrow += redsum_hi(ps);

        // P -> per-wave LDS (4x b64)
#pragma unroll
        for (int tt = 0; tt < 4; ++tt) {
            uint2 pw = { pack2bf(s[tt][0], s[tt][1]), pack2bf(s[tt][2], s[tt][3]) };
            *(uint2*)&Pl[w][fr][tt * 16 + hi * 4] = pw;
        }

        // O^T += V^T * P
#pragma unroll
        for (int c = 0; c < 2; ++c) {
            sh8 pa = *(const sh8*)&Pl[w][fr][c * 32 + hi * 8];
            __builtin_amdgcn_s_setprio(1);
#pragma unroll
            for (int df = 0; df < 4; ++df) {
                int d = df * 16 + fr;
                int fd = (d & 7) ^ (d >> 3);
                sh8 vfr = *(const sh8*)&Vt[d][((4 * c + hi) ^ fd) * 8];
                acc[df] = MFMA16(vfr, pa, acc[df]);
            }
            __builtin_amdgcn_s_setprio(0);
        }
    }

    {
        float inv = 1.0f / lrow;
        long qr = base + q0 + w * 16 + fr;
        unsigned short* op = &ao[qr * 1024 + h * 64];
#pragma unroll
        for (int df = 0; df < 4; ++df) {
            f32x4 o = acc[df];
            uint2 ow = { pack2bf(o[0] * inv, o[1] * inv), pack2bf(o[2] * inv, o[3] * inv) };
            *(uint2*)&op[df * 16 + hi * 4] = ow;
        }
    }
}

// ---------------------------------------------------------------------------
// Output projection, m97-style staging (unchanged).
// ---------------------------------------------------------------------------
__global__ __launch_bounds__(256) void gemm_out_k(
    const unsigned short* __restrict__ ao, const unsigned short* __restrict__ wob,
    const float* __restrict__ bo, float* __restrict__ out)
{
    __shared__ unsigned short As[128][32];
    __shared__ unsigned short Bs[128][32];
    const int tid = threadIdx.x;
    const int l = tid & 63, w = tid >> 6;
    const int wr = w >> 1, wc = w & 1;
    const long row0 = (long)blockIdx.y * 128;
    const int col0 = blockIdx.x * 128;

    f32x4 acc[4][4] = {};
    const int fr = l & 15, hi = l >> 4;

    const int sr = tid >> 2;
    const int sc = (tid & 3) * 8;
    const unsigned short* ga = &ao[(row0 + sr) * 1024 + sc];
    const unsigned short* gb = &wob[(long)(col0 + sr) * 1024 + sc];
    unsigned short* la = &As[w * 16][0];
    unsigned short* lb = &Bs[w * 16][0];

    for (int k0 = 0; k0 < 1024; k0 += 32) {
        __syncthreads();
        gload_lds16(ga + k0, la);
        gload_lds16(ga + 64 * 1024 + k0, la + 64 * 32);
        gload_lds16(gb + k0, lb);
        gload_lds16(gb + 64 * 1024 + k0, lb + 64 * 32);
        __syncthreads();

        sh8 af[4], bf[4];
#pragma unroll
        for (int i = 0; i < 4; ++i) {
            af[i] = *(const sh8*)&As[wr * 64 + i * 16 + fr][hi * 8];
            bf[i] = *(const sh8*)&Bs[wc * 64 + i * 16 + fr][hi * 8];
        }
#pragma unroll
        for (int i = 0; i < 4; ++i)
#pragma unroll
            for (int j = 0; j < 4; ++j)
                acc[i][j] = MFMA16(af[i], bf[j], acc[i][j]);
    }

    const int rg = hi * 4, cg = l & 15;
#pragma unroll
    for (int i = 0; i < 4; ++i)
#pragma unroll
        for (int j = 0; j < 4; ++j) {
            long gr = row0 + wr * 64 + i * 16 + rg;
            int gc = col0 + wc * 64 + j * 16 + cg;
            float bb = bo[gc];
#pragma unroll
            for (int r = 0; r < 4; ++r)
                out[(gr + r) * 1024 + gc] = acc[i][j][r] + bb;
        }
}

extern "C" void kernel_launch(void* const* d_in, const int* in_sizes, int n_in,
                              void* d_out, int out_size, void* d_ws, size_t ws_size,
                              hipStream_t stream) {
    const float* x    = (const float*)d_in[0];
    const int*   mask = (const int*)d_in[1];
    const float* Wq   = (const float*)d_in[2];
    const float* Wk   = (const float*)d_in[3];
    const float* Wv   = (const float*)d_in[4];
    const float* Wo   = (const float*)d_in[5];
    const float* bo   = (const float*)d_in[6];
    float* out = (float*)d_out;

    const size_t wbf_bytes = (size_t)4096 * 1024 * 2;              // 8 MiB
    const size_t idx_bytes = (size_t)4 * 2048 * 4 + 64;
    const size_t seg_b = (size_t)2048 * 1024 * 2;                  // 4 MiB
    // per batch: xbf + xc + qb + Kck + Vtg + ao = 6 segments = 24 MiB
    const size_t per_b = 6 * seg_b;

    size_t fixed = wbf_bytes + idx_bytes;
    size_t avail = (ws_size > fixed) ? (ws_size - fixed) : 0;
    int bchunk = (avail >= per_b) ? (int)(avail / per_b) : 1;
    if (bchunk > 4) bchunk = 4;

    char* p = (char*)d_ws;
    unsigned short* wbf = (unsigned short*)p;            p += wbf_bytes;
    int* idxp = (int*)p;                                 p += (size_t)4 * 2048 * 4;
    int* cntp = (int*)p;                                 p += 64;
    unsigned short* xbf = (unsigned short*)p;            p += (size_t)bchunk * seg_b;
    unsigned short* xc  = (unsigned short*)p;            p += (size_t)bchunk * seg_b;
    unsigned short* qbp = (unsigned short*)p;            p += (size_t)bchunk * seg_b;
    unsigned short* Kck = (unsigned short*)p;            p += (size_t)bchunk * seg_b;
    unsigned short* Vtg = (unsigned short*)p;            p += (size_t)bchunk * seg_b;
    unsigned short* ao  = (unsigned short*)p;

    for (int b0 = 0; b0 < 4; b0 += bchunk) {
        int bc = (4 - b0 < bchunk) ? (4 - b0) : bchunk;
        prep_k<<<4096 + 4 + 2048, 256, 0, stream>>>(
            x + (size_t)b0 * 2048 * 1024, Wq, Wk, Wv, Wo, mask,
            wbf, xbf, idxp, cntp, bc * 524288);
        xgather_k<<<dim3(8, 32, bc), 256, 0, stream>>>(xbf, idxp, cntp, xc, b0);
        gemm_proj_k<<<dim3(24, 16 * bc), 256, 0, stream>>>(
            xbf, xc, wbf, cntp, b0, qbp, Kck, Vtg);
        attn_k<<<dim3(512 * bc), 256, 0, stream>>>(qbp, Kck, Vtg, cntp, ao, b0);
        gemm_out_k<<<dim3(8, bc * 16), 256, 0, stream>>>(
            ao, wbf + (size_t)3072 * 1024, bo, out + (size_t)b0 * 2048 * 1024);
    }
}